// Round 2
// baseline (129.239 us; speedup 1.0000x reference)
//
#include <hip/hip_runtime.h>

// Depthwise 21x21 Gaussian blur, reflection pad 10, on 16x3x512x512 fp32.
// Exploits separability: K = outer(phi,phi); phi recovered from W row 10:
//   phi[j] = W[ch][10][j] / sqrt(W[ch][10][10])
// Fused single kernel: global -> LDS tile (84x84 w/ halo, reflect) ->
// horizontal 21-tap pass -> transposed LDS intermediate -> vertical 21-tap
// pass -> global. Sliding-window register accumulation: each thread makes
// 16 contiguous outputs from 36 LDS reads (vs 16*21=336 naive).
// All LDS patterns are uniform 2-way (free on CDNA4, stride 85: 21 mod 32
// coprime). LDS 50.4 KB -> 3 blocks/CU, 12 waves/CU.

constexpr int IMG  = 512;
constexpr int KS   = 21;
constexpr int RAD  = 10;
constexpr int TILE = 64;
constexpr int HALO = TILE + 2 * RAD;      // 84
constexpr int SA_STRIDE = 85;
constexpr int SB_STRIDE = 85;

__global__ __launch_bounds__(256, 3) void gauss2d_sep(const float* __restrict__ x,
                                                      const float* __restrict__ W,
                                                      float* __restrict__ out)
{
    __shared__ float sA[HALO * SA_STRIDE];   // input tile [row][col], 28.6 KB
    __shared__ float sB[TILE * SB_STRIDE];   // h-filtered, TRANSPOSED [col][row], 21.8 KB
    __shared__ float sPhi[KS];

    const int tid = threadIdx.x;
    const int tx  = blockIdx.x * TILE;
    const int ty  = blockIdx.y * TILE;
    const int bc  = blockIdx.z;              // batch*3 + channel
    const int ch  = bc % 3;

    // Recover separable 1D taps from the 2D weight (center row / sqrt(center)).
    if (tid < KS) {
        const float* wr = W + ch * (KS * KS) + RAD * KS;
        sPhi[tid] = wr[tid] / sqrtf(wr[RAD]);
    }

    const float* __restrict__ xin = x + (size_t)bc * (IMG * IMG);

    // ---- Stage 84x84 input tile with reflection padding (coalesced rows) ----
    for (int e = tid; e < HALO * HALO; e += 256) {
        int r = e / HALO, c = e - r * HALO;
        int gr = ty + r - RAD;
        int gc = tx + c - RAD;
        gr = (gr < 0) ? -gr : gr;  gr = (gr >= IMG) ? 2 * IMG - 2 - gr : gr;
        gc = (gc < 0) ? -gc : gc;  gc = (gc >= IMG) ? 2 * IMG - 2 - gc : gc;
        sA[r * SA_STRIDE + c] = xin[gr * IMG + gc];
    }
    __syncthreads();

    float ph[KS];
    #pragma unroll
    for (int j = 0; j < KS; ++j) ph[j] = sPhi[j];

    // ---- Horizontal pass: 84 rows x 64 cols. Task = (row, 16-col chunk). ----
    // 336 tasks over 256 threads. Sliding window: 36 LDS reads -> 16 outputs.
    for (int e = tid; e < HALO * 4; e += 256) {
        int r  = e >> 2;
        int c0 = (e & 3) * 16;
        const float* arow = &sA[r * SA_STRIDE + c0];
        float acc[16];
        #pragma unroll
        for (int i = 0; i < 16; ++i) acc[i] = 0.f;
        #pragma unroll
        for (int k = 0; k < KS + 15; ++k) {          // 36 input samples
            float v = arow[k];
            #pragma unroll
            for (int i = 0; i < 16; ++i) {
                int j = k - i;
                if (j >= 0 && j < KS) acc[i] += ph[j] * v;   // compile-time guard
            }
        }
        #pragma unroll
        for (int i = 0; i < 16; ++i)
            sB[(c0 + i) * SB_STRIDE + r] = acc[i];   // transposed store, 2-way max
    }
    __syncthreads();

    // ---- Vertical pass: thread -> col = tid&63, rows [(tid>>6)*16, +16) ----
    {
        int c  = tid & 63;
        int r0 = (tid >> 6) * 16;
        const float* bcol = &sB[c * SB_STRIDE + r0];
        float acc[16];
        #pragma unroll
        for (int i = 0; i < 16; ++i) acc[i] = 0.f;
        #pragma unroll
        for (int k = 0; k < KS + 15; ++k) {
            float v = bcol[k];
            #pragma unroll
            for (int i = 0; i < 16; ++i) {
                int j = k - i;
                if (j >= 0 && j < KS) acc[i] += ph[j] * v;
            }
        }
        float* __restrict__ oimg = out + (size_t)bc * (IMG * IMG)
                                 + (size_t)(ty + r0) * IMG + (tx + c);
        #pragma unroll
        for (int i = 0; i < 16; ++i)
            oimg[i * IMG] = acc[i];                  // coalesced: wave spans 64 cols
    }
}

extern "C" void kernel_launch(void* const* d_in, const int* in_sizes, int n_in,
                              void* d_out, int out_size, void* d_ws, size_t ws_size,
                              hipStream_t stream) {
    const float* x = (const float*)d_in[0];
    const float* W = (const float*)d_in[1];
    float* out     = (float*)d_out;
    dim3 grid(IMG / TILE, IMG / TILE, 16 * 3);
    gauss2d_sep<<<grid, 256, 0, stream>>>(x, W, out);
}

// Round 3
// 123.424 us; speedup vs baseline: 1.0471x; 1.0471x over previous
//
#include <hip/hip_runtime.h>

// Depthwise 21x21 Gaussian blur, reflect pad 10, 16x3x512x512 fp32.
// Separable: phi[j] = W[ch][10][j] / sqrt(W[ch][10][10]).
// R2 changes vs R1: 64x32 tile -> LDS 31.3KB -> 5 blocks/CU (20 waves, was 12);
// staging address math reduced ~4x (no div/mod per element, col-reflect hoisted);
// taps pinned to SGPRs via readfirstlane. All LDS patterns uniform 2-way (free).

constexpr int IMG = 512;
constexpr int KS  = 21;
constexpr int RAD = 10;
constexpr int TX  = 64;
constexpr int TY  = 32;
constexpr int HY  = TY + 2 * RAD;     // 52 halo rows
constexpr int SA_STRIDE = 85;         // 84 cols + 1 (85%32=21, coprime)
constexpr int SB_STRIDE = 53;         // 52 rows + 1 (53%32=21, coprime)

__global__ __launch_bounds__(256, 5) void gauss2d_sep(const float* __restrict__ x,
                                                      const float* __restrict__ W,
                                                      float* __restrict__ out)
{
    __shared__ float sA[HY * SA_STRIDE];   // [row][col] 17.7 KB
    __shared__ float sB[TX * SB_STRIDE];   // [col][row] transposed, 13.6 KB
    __shared__ float sPhi[KS];

    const int tid = threadIdx.x;
    const int tx  = blockIdx.x * TX;
    const int ty  = blockIdx.y * TY;
    const int bc  = blockIdx.z;            // batch*3 + channel
    const int ch  = bc % 3;

    if (tid < KS) {
        const float* wr = W + ch * (KS * KS) + RAD * KS;
        sPhi[tid] = wr[tid] / sqrtf(wr[RAD]);
    }

    const float* __restrict__ xin = x + (size_t)bc * (IMG * IMG);

    // ---- Stage 52x84 input tile, reflect pad. 252 threads = 84 cols x 3 rgroups.
    if (tid < 252) {
        const int rg = (tid >= 168) ? 2 : (tid >= 84 ? 1 : 0);
        const int c  = tid - rg * 84;
        int gc = tx + c - RAD;                       // col reflect hoisted
        gc = (gc < 0) ? -gc : gc;
        gc = (gc >= IMG) ? 2 * IMG - 2 - gc : gc;
        for (int rr = rg; rr < HY; rr += 3) {
            int gr = ty + rr - RAD;
            gr = (gr < 0) ? -gr : gr;
            gr = (gr >= IMG) ? 2 * IMG - 2 - gr : gr;
            sA[rr * SA_STRIDE + c] = xin[gr * IMG + gc];
        }
    }
    __syncthreads();

    // Taps -> wave-uniform (SGPR) registers.
    float ph[KS];
    #pragma unroll
    for (int j = 0; j < KS; ++j)
        ph[j] = __int_as_float(__builtin_amdgcn_readfirstlane(__float_as_int(sPhi[j])));

    // ---- Horizontal pass: 52 rows x 4 chunks of 16 cols = 208 tasks. ----
    // Sliding window: 36 LDS reads -> 16 outputs; store transposed.
    if (tid < HY * 4) {
        const int r  = tid >> 2;
        const int c0 = (tid & 3) << 4;
        const float* arow = &sA[r * SA_STRIDE + c0];
        float acc[16];
        #pragma unroll
        for (int i = 0; i < 16; ++i) acc[i] = 0.f;
        #pragma unroll
        for (int k = 0; k < KS + 15; ++k) {
            const float v = arow[k];
            #pragma unroll
            for (int i = 0; i < 16; ++i) {
                const int j = k - i;
                if (j >= 0 && j < KS) acc[i] += ph[j] * v;   // compile-time guard
            }
        }
        #pragma unroll
        for (int i = 0; i < 16; ++i)
            sB[(c0 + i) * SB_STRIDE + r] = acc[i];           // 2-way max
    }
    __syncthreads();

    // ---- Vertical pass: col = tid&63, rows [(tid>>6)*8, +8). 256 tasks. ----
    {
        const int c  = tid & 63;
        const int r0 = (tid >> 6) << 3;
        const float* bcol = &sB[c * SB_STRIDE + r0];
        float acc[8];
        #pragma unroll
        for (int i = 0; i < 8; ++i) acc[i] = 0.f;
        #pragma unroll
        for (int k = 0; k < KS + 7; ++k) {
            const float v = bcol[k];
            #pragma unroll
            for (int i = 0; i < 8; ++i) {
                const int j = k - i;
                if (j >= 0 && j < KS) acc[i] += ph[j] * v;
            }
        }
        float* __restrict__ oimg = out + (size_t)bc * (IMG * IMG)
                                 + (size_t)(ty + r0) * IMG + (tx + c);
        #pragma unroll
        for (int i = 0; i < 8; ++i)
            oimg[i * IMG] = acc[i];                          // fully coalesced
    }
}

extern "C" void kernel_launch(void* const* d_in, const int* in_sizes, int n_in,
                              void* d_out, int out_size, void* d_ws, size_t ws_size,
                              hipStream_t stream) {
    const float* x = (const float*)d_in[0];
    const float* W = (const float*)d_in[1];
    float* out     = (float*)d_out;
    dim3 grid(IMG / TX, IMG / TY, 16 * 3);
    gauss2d_sep<<<grid, 256, 0, stream>>>(x, W, out);
}